// Round 6
// baseline (521.499 us; speedup 1.0000x reference)
//
#include <hip/hip_runtime.h>
#include <hip/hip_bf16.h>

// GCN 4-layer, linear network => collapse to:
// out = A^4 x0 * c4 + A^3 1 * c3 + A^2 1 * c2 + A 1 * c1 + b4,
// A = D^-1/2 (Adj+I) D^-1/2. Propagate in scaled space u' = D^-1 (Adj+I) u,
// epilogue multiplies sqrt(deg). Channels (x-path, ones-path) packed float2.
// Dtypes (R1-R4 verified): read_length int32, edge_index int32, W/b fp32, out fp32.
//
// R13: bucket-resident edge-parallel gather. R12 counters: gather sweeps at
// 1.6TB/s, VALUBusy 12% -> latency-bound; FETCH is only ~20% over the
// compulsory floor (vin = 4MB x 8 private L2s = 32MB + epart 32MB), so the
// lever is MLP not traffic. New gather: one 1024-thread block per bucket,
// float2 acc[1024] in LDS (8KB), threads sweep the bucket's contiguous edge
// run (coalesced, unroll-4 -> 4 independent vin lines in flight/thread,
// no dependent rowp chain), accumulate via native ds_add_f32. Needs only
// bucket-grouped edges -> csr_build + rowp DELETED (~30us); degree from a
// fused deg_init count pass (+15us). Old R5/R6 LDS-atomic null was on the
// pre-bucket 19%-occupancy structure; this one runs 2048 thr/CU.

#define BLK  256
#define SBLK 1024         // scatter/count block
#define NB   512          // buckets
#define BSH  10           // bucket = dst >> 10  (1024 nodes / bucket)
#define PB   512          // partition blocks
#define BUFCAP 15872      // scatter LDS sort buffer (chunk = ceil(8M/512) = 15625)

// If rl were int64 (values in [0,20000)), every odd int32 word is 0.
__global__ void probe_i64(const int* __restrict__ rl32, int* __restrict__ flag) {
    __shared__ int sm[BLK];
    int t = threadIdx.x;
    int acc = 0;
    for (int k = t; k < 1024; k += blockDim.x)
        acc |= rl32[2 * k + 1];
    sm[t] = acc; __syncthreads();
    for (int off = BLK / 2; off > 0; off >>= 1) {
        if (t < off) sm[t] |= sm[t + off];
        __syncthreads();
    }
    if (t == 0) *flag = (sm[0] != 0) ? 1 : 0;   // 1 => int32 layout
}

__global__ __launch_bounds__(SBLK)
void bucket_count(const int* __restrict__ dst, int* __restrict__ table, int E) {
    __shared__ int h[NB];
    int j = blockIdx.x, t = threadIdx.x;
    for (int b = t; b < NB; b += SBLK) h[b] = 0;
    __syncthreads();
    int chunk = (E + PB - 1) / PB;
    int beg = j * chunk, end = min(beg + chunk, E);
    for (int e = beg + t; e < end; e += SBLK)
        atomicAdd(&h[((unsigned)dst[e]) >> BSH], 1);
    __syncthreads();
    for (int b = t; b < NB; b += SBLK) table[j * NB + b] = h[b];   // coalesced
}

// one block per bucket, LDS tree reduce
__global__ void bucket_tot(const int* __restrict__ table, int* __restrict__ tot) {
    __shared__ int sm[BLK];
    int b = blockIdx.x, t = threadIdx.x;
    int s = 0;
    for (int j = t; j < PB; j += BLK) s += table[j * NB + b];
    sm[t] = s; __syncthreads();
    for (int off = BLK / 2; off > 0; off >>= 1) {
        if (t < off) sm[t] += sm[t + off];
        __syncthreads();
    }
    if (t == 0) tot[b] = sm[0];
}

// one block (1 wave) per bucket; lane owns 8 consecutive j-slots, shfl
// prefix scan across lanes. base[b] computed in-wave from btot.
// table[j][b] := base[b]+sum_{j'<j}. Note: after this, table[0][b] = base[b]
// — row 0 doubles as the bucket-base array for the gather kernels.
__global__ __launch_bounds__(64)
void scan_table(int* __restrict__ table, const int* __restrict__ btot) {
    int b = blockIdx.x, lane = threadIdx.x;
    // base[b] = sum_{k<b} btot[k]
    int pre = 0;
    for (int k = lane; k < NB; k += 64)
        if (k < b) pre += btot[k];
    for (int off = 1; off < 64; off <<= 1) pre += __shfl_xor(pre, off);
    int v[PB / 64]; int s = 0;
#pragma unroll
    for (int k = 0; k < PB / 64; ++k) {
        v[k] = table[(lane * (PB / 64) + k) * NB + b];
        s += v[k];
    }
    int run = s;
    for (int off = 1; off < 64; off <<= 1) {
        int u = __shfl_up(run, off);
        if (lane >= off) run += u;
    }
    run -= s;                 // exclusive over lanes
    run += pre;
#pragma unroll
    for (int k = 0; k < PB / 64; ++k) {
        int t = v[k];
        table[(lane * (PB / 64) + k) * NB + b] = run;
        run += t;
    }
}

// R9: block-local counting sort; emit bucket runs with dense coalesced stores.
__global__ __launch_bounds__(SBLK)
void scatter(const int* __restrict__ src, const int* __restrict__ dst,
             const int* __restrict__ table, unsigned* __restrict__ epart, int E) {
    __shared__ unsigned buf[BUFCAP];     // 62 KB
    __shared__ int h[NB];                // per-subchunk counts
    __shared__ int cur[NB];              // scan / fill cursor
    __shared__ int rbase[NB];            // running global base per bucket
    int j = blockIdx.x, t = threadIdx.x;
    for (int b = t; b < NB; b += SBLK) rbase[b] = table[j * NB + b];
    int chunk = (E + PB - 1) / PB;
    int beg = j * chunk, end = min(beg + chunk, E);
    for (int s = beg; s < end; s += BUFCAP) {
        int se = min(s + BUFCAP, end);
        for (int b = t; b < NB; b += SBLK) h[b] = 0;
        __syncthreads();
        for (int e = s + t; e < se; e += SBLK)
            atomicAdd(&h[((unsigned)dst[e]) >> BSH], 1);
        __syncthreads();
        // inclusive scan of h into cur (NB entries, Hillis-Steele)
        if (t < NB) cur[t] = h[t];
        __syncthreads();
        for (int off = 1; off < NB; off <<= 1) {
            int add = 0;
            if (t < NB && t >= off) add = cur[t - off];
            __syncthreads();
            if (t < NB) cur[t] += add;
            __syncthreads();
        }
        if (t < NB) cur[t] -= h[t];      // exclusive start
        __syncthreads();
        // fill LDS buffer sorted by bucket
        for (int e = s + t; e < se; e += SBLK) {
            unsigned d = (unsigned)dst[e];
            int b = d >> BSH;
            int slot = atomicAdd(&cur[b], 1);
            buf[slot] = ((d & 1023u) << 19) | (unsigned)src[e];
        }
        __syncthreads();
        // copy out: wave w handles buckets w, w+16, ... (runs are contiguous)
        int w = t >> 6, lane = t & 63;
        for (int b = w; b < NB; b += (SBLK >> 6)) {
            int n = h[b];
            int lo = cur[b] - n;         // cur is back to inclusive after fill
            int gb = rbase[b];
            for (int k = lane; k < n; k += 64)
                epart[gb + k] = buf[lo + k];
        }
        __syncthreads();
        if (t < NB) rbase[t] += h[t];
        __syncthreads();
    }
}

// R13: per-bucket degree count + node init (+ coeffs in the last block).
__global__ __launch_bounds__(1024)
void deg_init(const unsigned* __restrict__ epart, const int* __restrict__ bbase,
              const int* __restrict__ rl, const int* __restrict__ flag,
              float* __restrict__ dinv, float2* __restrict__ v0, int N,
              const float* __restrict__ W1, const float* __restrict__ b1,
              const float* __restrict__ W2, const float* __restrict__ b2,
              const float* __restrict__ W3, const float* __restrict__ b3,
              const float* __restrict__ W4, const float* __restrict__ b4,
              float* __restrict__ c) {
    __shared__ int cnt[1024];
    __shared__ float p3[16], q3[16], r3[16];
    int b = blockIdx.x, t = threadIdx.x;
    if (b == gridDim.x - 1) {
        // coeffs block
        if (t == 0) {
            float p2[8], q2[8];
            for (int j = 0; j < 8; ++j) {
                float s1 = 0.f, s2 = 0.f;
                for (int k = 0; k < 4; ++k) {
                    float w = W2[k * 8 + j];
                    s1 += W1[k] * w;
                    s2 += b1[k] * w;
                }
                p2[j] = s1; q2[j] = s2;
            }
            for (int m = 0; m < 16; ++m) {
                float s1 = 0.f, s2 = 0.f, s3 = 0.f;
                for (int j = 0; j < 8; ++j) {
                    float w = W3[j * 16 + m];
                    s1 += p2[j] * w; s2 += q2[j] * w;
                    s3 += b2[j] * w;
                }
                p3[m] = s1; q3[m] = s2; r3[m] = s3;
            }
        }
        __syncthreads();
        if (t < 32) {
            float c4 = 0.f, c3 = 0.f, c2 = 0.f, c1 = 0.f;
            for (int k = 0; k < 16; ++k) {
                float w = W4[k * 32 + t];
                c4 += p3[k] * w; c3 += q3[k] * w; c2 += r3[k] * w;
                c1 += b3[k] * w;
            }
            c[t] = c4; c[32 + t] = c3; c[64 + t] = c2; c[96 + t] = c1;
        }
        return;
    }
    cnt[t] = 0;
    __syncthreads();
    int e = bbase[b] + t, end = bbase[b + 1];
    for (; e < end; e += 1024)
        atomicAdd(&cnt[epart[e] >> 19], 1);
    __syncthreads();
    int gi = (b << 10) + t;
    if (gi < N) {
        int v = (*flag) ? rl[gi] : rl[2 * gi];
        float d = (float)cnt[t] + 1.0f;   // + self-loop
        dinv[gi] = 1.0f / d;
        float rs = rsqrtf(d);
        float2 u; u.x = rs * ((float)v * (1.0f / 20000.0f)); u.y = rs;
        v0[gi] = u;
    }
}

// R13: one sweep = one block per bucket; edge-parallel, LDS float accumulate.
// epart reads coalesced; 4 independent vin lines in flight per thread.
__global__ __launch_bounds__(1024)
void gather_lds(const unsigned* __restrict__ epart, const int* __restrict__ bbase,
                const float2* __restrict__ vin, float2* __restrict__ vout,
                const float* __restrict__ dinv, float* __restrict__ zsave, int N) {
    __shared__ float ax[1024];
    __shared__ float ay[1024];
    int b = blockIdx.x, t = threadIdx.x;
    ax[t] = 0.f; ay[t] = 0.f;
    __syncthreads();
    int e = bbase[b] + t, end = bbase[b + 1];
    for (; e + 3072 < end; e += 4096) {
        unsigned p0 = epart[e], p1 = epart[e + 1024],
                 p2 = epart[e + 2048], p3 = epart[e + 3072];
        float2 u0 = vin[p0 & 0x7FFFFu];
        float2 u1 = vin[p1 & 0x7FFFFu];
        float2 u2 = vin[p2 & 0x7FFFFu];
        float2 u3 = vin[p3 & 0x7FFFFu];
        atomicAdd(&ax[p0 >> 19], u0.x); atomicAdd(&ay[p0 >> 19], u0.y);
        atomicAdd(&ax[p1 >> 19], u1.x); atomicAdd(&ay[p1 >> 19], u1.y);
        atomicAdd(&ax[p2 >> 19], u2.x); atomicAdd(&ay[p2 >> 19], u2.y);
        atomicAdd(&ax[p3 >> 19], u3.x); atomicAdd(&ay[p3 >> 19], u3.y);
    }
    for (; e < end; e += 1024) {
        unsigned p = epart[e];
        float2 u = vin[p & 0x7FFFFu];
        atomicAdd(&ax[p >> 19], u.x); atomicAdd(&ay[p >> 19], u.y);
    }
    __syncthreads();
    int gi = (b << 10) + t;
    if (gi < N) {
        float2 self = vin[gi];
        float di = dinv[gi];
        float2 o; o.x = (ax[t] + self.x) * di; o.y = (ay[t] + self.y) * di;
        vout[gi] = o;
        if (zsave) zsave[gi] = o.y;
    }
}

// R13: fused final sweep + epilogue (x-channel only). After accumulation,
// acc/sq are republished in LDS and the epilogue goes channel-parallel
// (32 threads/node) for coalesced 128B stores. Valid only when epart is in
// workspace (out aliases d_out).
__global__ __launch_bounds__(1024)
void gather_out_lds(const unsigned* __restrict__ epart, const int* __restrict__ bbase,
                    const float2* __restrict__ vin, const float* __restrict__ dinv,
                    const float* __restrict__ z1, const float* __restrict__ z2,
                    const float* __restrict__ z3, const float* __restrict__ c,
                    const float* __restrict__ b4, float* __restrict__ out, int N) {
    __shared__ float ax[1024];
    __shared__ float sqs[1024];
    int b = blockIdx.x, t = threadIdx.x;
    ax[t] = 0.f;
    __syncthreads();
    int e = bbase[b] + t, end = bbase[b + 1];
    for (; e + 3072 < end; e += 4096) {
        unsigned p0 = epart[e], p1 = epart[e + 1024],
                 p2 = epart[e + 2048], p3 = epart[e + 3072];
        float x0 = vin[p0 & 0x7FFFFu].x;
        float x1 = vin[p1 & 0x7FFFFu].x;
        float x2 = vin[p2 & 0x7FFFFu].x;
        float x3 = vin[p3 & 0x7FFFFu].x;
        atomicAdd(&ax[p0 >> 19], x0);
        atomicAdd(&ax[p1 >> 19], x1);
        atomicAdd(&ax[p2 >> 19], x2);
        atomicAdd(&ax[p3 >> 19], x3);
    }
    for (; e < end; e += 1024) {
        unsigned p = epart[e];
        atomicAdd(&ax[p >> 19], vin[p & 0x7FFFFu].x);
    }
    __syncthreads();
    int gi = (b << 10) + t;
    float ox = 0.f, sq = 0.f;
    if (gi < N) {
        float di = dinv[gi];
        ox = (ax[t] + vin[gi].x) * di;   // final A^4 x (scaled space)
        sq = rsqrtf(di);                 // = sqrt(deg)
    }
    ax[t] = ox; sqs[t] = sq;             // own slot only — no race
    __syncthreads();
    // channel-parallel epilogue: f fixed per thread, 2 nodes per wave
    int f = t & 31, half = t >> 5;       // half in [0,32)
    float c4 = c[f], c3 = c[32 + f], c2 = c[64 + f], c1 = c[96 + f], bb = b4[f];
    int base_node = b << 10;
    for (int p = 0; p < 32; ++p) {
        int ln = p * 32 + half;
        int g = base_node + ln;
        if (g < N) {
            float zz1 = z1[g], zz2 = z2[g], zz3 = z3[g];
            float val = sqs[ln] * (ax[ln] * c4 + zz3 * c3 + zz2 * c2 + zz1 * c1) + bb;
            out[(size_t)g * 32 + f] = val;
        }
    }
}

// fallback epilogue (split path)
__global__ void write_out(const float2* __restrict__ v0, const float* __restrict__ z1,
                          const float* __restrict__ z2, const float* __restrict__ z3,
                          const float* __restrict__ dinv, const float* __restrict__ c,
                          const float* __restrict__ b4,
                          float* __restrict__ out, int N) {
    int t = blockIdx.x * blockDim.x + threadIdx.x;
    int i = t >> 5, f = t & 31;
    if (i < N) {
        float sq = rsqrtf(dinv[i]);  // = sqrt(deg)
        float v = sq * (v0[i].x * c[f] + z3[i] * c[32 + f] + z2[i] * c[64 + f]
                        + z1[i] * c[96 + f])
                  + b4[f];
        out[(size_t)i * 32 + f] = v;
    }
}

extern "C" void kernel_launch(void* const* d_in, const int* in_sizes, int n_in,
                              void* d_out, int out_size, void* d_ws, size_t ws_size,
                              hipStream_t stream) {
    const int N = in_sizes[0];
    const int E = in_sizes[1] / 2;
    const int* rl  = (const int*)d_in[0];
    const int* src = (const int*)d_in[1];
    const int* dst = src + E;
    const float* W1 = (const float*)d_in[2];
    const float* b1 = (const float*)d_in[3];
    const float* W2 = (const float*)d_in[4];
    const float* b2 = (const float*)d_in[5];
    const float* W3 = (const float*)d_in[6];
    const float* b3 = (const float*)d_in[7];
    const float* W4 = (const float*)d_in[8];
    const float* b4 = (const float*)d_in[9];

    const int gbNode = (N + 1023) / 1024;     // buckets containing nodes (489)

    // workspace layout
    char* w = (char*)d_ws;
    float2* v0   = (float2*)w;                w += (size_t)N * 8;
    float2* v1   = (float2*)w;                w += (size_t)N * 8;
    float*  dinv = (float*)w;                 w += (size_t)N * 4;
    float*  z1   = (float*)w;                 w += (size_t)N * 4;
    float*  z2   = (float*)w;                 w += (size_t)N * 4;
    float*  z3   = (float*)w;                 w += (size_t)N * 4;
    int*    table = (int*)w;                  w += (size_t)PB * NB * 4;
    int*    btot  = (int*)w;                  w += NB * 4;
    float*  c     = (float*)w;                w += 128 * 4;
    int*    flag  = (int*)w;                  w += 16;
    // epart in workspace if it fits (enables fused gather_out_lds)
    size_t used = (size_t)(w - (char*)d_ws);
    used = (used + 255) & ~(size_t)255;
    bool fits = (used + (size_t)E * 4) <= ws_size;
    unsigned* epart = fits ? (unsigned*)((char*)d_ws + used) : (unsigned*)d_out;

    probe_i64<<<1, BLK, 0, stream>>>(rl, flag);

    // radix partition by dst bucket — zero global atomics
    bucket_count<<<PB, SBLK, 0, stream>>>(dst, table, E);
    bucket_tot<<<NB, BLK, 0, stream>>>(table, btot);
    scan_table<<<NB, 64, 0, stream>>>(table, btot);
    scatter<<<PB, SBLK, 0, stream>>>(src, dst, table, epart, E);

    // degree + node init (+ coeffs). table row 0 = bucket base offsets.
    deg_init<<<gbNode + 1, 1024, 0, stream>>>(epart, table, rl, flag, dinv, v0, N,
                                              W1, b1, W2, b2, W3, b3, W4, b4, c);

    // 4 propagation sweeps, ping-pong v0<->v1 (bucket-resident LDS accumulate)
    gather_lds<<<gbNode, 1024, 0, stream>>>(epart, table, v0, v1, dinv, z1, N);
    gather_lds<<<gbNode, 1024, 0, stream>>>(epart, table, v1, v0, dinv, z2, N);
    gather_lds<<<gbNode, 1024, 0, stream>>>(epart, table, v0, v1, dinv, z3, N);
    if (fits) {
        gather_out_lds<<<gbNode, 1024, 0, stream>>>(epart, table, v1, dinv,
                                                    z1, z2, z3, c, b4,
                                                    (float*)d_out, N);
    } else {
        gather_lds<<<gbNode, 1024, 0, stream>>>(epart, table, v1, v0, dinv,
                                                (float*)nullptr, N);
        write_out<<<(N * 32 + BLK - 1) / BLK, BLK, 0, stream>>>(
            v0, z1, z2, z3, dinv, c, b4, (float*)d_out, N);
    }
}

// Round 7
// 403.199 us; speedup vs baseline: 1.2934x; 1.2934x over previous
//
#include <hip/hip_runtime.h>
#include <hip/hip_bf16.h>

// GCN 4-layer, linear network => collapse to:
// out = A^4 x0 * c4 + A^3 1 * c3 + A^2 1 * c2 + A 1 * c1 + b4,
// A = D^-1/2 (Adj+I) D^-1/2. Propagate in scaled space u' = D^-1 (Adj+I) u,
// epilogue multiplies sqrt(deg). Channels (x-path, ones-path) packed float2.
// Dtypes (R1-R4 verified): read_length int32, edge_index int32, W/b fp32, out fp32.
//
// R14: (a) REVERT R13 (LDS-atomic gather = 92us vs 52: LDS float atomics
// retire ~1 lane-op/cycle/CU -> 16M-atomic passes can't win; back to R12's
// register-reduce gather_csr + fused gather_out = 419us config).
// (b) Preprocessing: within-bucket order is irrelevant (csr_build re-sorts),
// so scatter reserves bucket space via one global atomicAdd(cur[b], n) per
// (block,bucket) run (~250K atomics) into fixed CAP segments, instead of
// exact precomputed destinations. DELETES bucket_count (32MB read + 8M LDS
// atomics), bucket_tot, scan_table, and the table array. csr_build gets
// compact offsets from cur[] via in-wave prefix; rowp is 1025-stride so each
// block owns all its entries (no cross-block boundary write).

#define BLK  256
#define SBLK 1024         // scatter block
#define NB   512          // buckets
#define BSH  10           // bucket = dst >> 10  (1024 nodes / bucket)
#define PB   512          // partition blocks
#define BUFCAP 15872      // scatter LDS sort buffer (chunk = ceil(8M/512) = 15625)
#define BUF2 18176        // csr_build LDS buffer (bucket mean 16384, sd ~128)
#define CAP  18432        // epart segment capacity per bucket (mean + 16 sigma)

// block 0: int64-layout probe (if rl were int64, every odd word is 0).
// block 1: zero the global bucket cursors.
__global__ void probe_i64(const int* __restrict__ rl32, int* __restrict__ flag,
                          int* __restrict__ cur) {
    __shared__ int sm[BLK];
    int t = threadIdx.x;
    if (blockIdx.x == 1) {
        for (int k = t; k < NB; k += BLK) cur[k] = 0;
        return;
    }
    int acc = 0;
    for (int k = t; k < 1024; k += blockDim.x)
        acc |= rl32[2 * k + 1];
    sm[t] = acc; __syncthreads();
    for (int off = BLK / 2; off > 0; off >>= 1) {
        if (t < off) sm[t] |= sm[t + off];
        __syncthreads();
    }
    if (t == 0) *flag = (sm[0] != 0) ? 1 : 0;   // 1 => int32 layout
}

// R14: single-pass scatter. Block-local LDS counting sort by bucket, then one
// global atomicAdd per bucket run reserves [pos, pos+n) in the bucket's fixed
// CAP segment; runs copied out dense+coalesced (lines written once, full).
__global__ __launch_bounds__(SBLK)
void scatter(const int* __restrict__ src, const int* __restrict__ dst,
             int* __restrict__ cur, unsigned* __restrict__ epart, int E) {
    __shared__ unsigned buf[BUFCAP];     // 62 KB
    __shared__ int h[NB];                // per-chunk counts
    __shared__ int c0[NB];               // scan / fill cursor
    __shared__ int gpos[NB];             // reserved global position
    int j = blockIdx.x, t = threadIdx.x;
    int chunk = (E + PB - 1) / PB;
    int beg = j * chunk, end = min(beg + chunk, E);
    for (int s = beg; s < end; s += BUFCAP) {
        int se = min(s + BUFCAP, end);
        for (int b = t; b < NB; b += SBLK) h[b] = 0;
        __syncthreads();
        for (int e = s + t; e < se; e += SBLK)
            atomicAdd(&h[((unsigned)dst[e]) >> BSH], 1);
        __syncthreads();
        // exclusive scan of h into c0 (NB entries, Hillis-Steele)
        if (t < NB) c0[t] = h[t];
        __syncthreads();
        for (int off = 1; off < NB; off <<= 1) {
            int add = 0;
            if (t < NB && t >= off) add = c0[t - off];
            __syncthreads();
            if (t < NB) c0[t] += add;
            __syncthreads();
        }
        if (t < NB) c0[t] -= h[t];
        __syncthreads();
        // fill LDS buffer sorted by bucket
        for (int e = s + t; e < se; e += SBLK) {
            unsigned d = (unsigned)dst[e];
            int b = d >> BSH;
            int slot = atomicAdd(&c0[b], 1);
            buf[slot] = ((d & 1023u) << 19) | (unsigned)src[e];
        }
        __syncthreads();
        // reserve global space: one thread per bucket
        if (t < NB) {
            int n = h[t];
            gpos[t] = (n > 0) ? atomicAdd(&cur[t], n) : 0;
        }
        __syncthreads();
        // copy out: wave w handles buckets w, w+16, ...
        int w = t >> 6, lane = t & 63;
        for (int b = w; b < NB; b += (SBLK >> 6)) {
            int n = h[b];
            int lo = c0[b] - n;          // c0 back to inclusive after fill
            int gp = gpos[b];
            int left = CAP - gp;         // overflow guard (unreachable)
            if (left < 0) left = 0;
            if (n > left) n = left;
            unsigned gb = (unsigned)b * CAP + (unsigned)gp;
            for (int k = lane; k < n; k += 64)
                epart[gb + k] = buf[lo + k];
        }
        __syncthreads();
    }
}

// within each bucket segment, order edges by local dst (CSR) and emit
// 1025-stride rowp. Compact output base from in-wave prefix over cur[].
// seg=0: write compact epart2 (disjoint buffer). seg=1: in-place into the
// segment (fallback path; safe: all reads precede writes via barriers).
__global__ __launch_bounds__(1024)
void csr_build(const unsigned* __restrict__ epart, const int* __restrict__ cur,
               unsigned* __restrict__ epart2, int* __restrict__ rowp, int seg) {
    __shared__ unsigned buf[BUF2];     // 71 KB
    __shared__ int sc[1024];
    __shared__ int cu[1024];
    __shared__ int s_beg, s_n;
    int b = blockIdx.x, t = threadIdx.x;
    if (t < 64) {
        int pre = 0, nn = 0;
        for (int k = t; k < NB; k += 64) {
            int v = min(cur[k], CAP);
            if (k < b) pre += v;
            if (k == b) nn = v;
        }
        for (int off = 1; off < 64; off <<= 1) {
            pre += __shfl_xor(pre, off);
            nn  += __shfl_xor(nn, off);
        }
        if (t == 0) { s_beg = pre; s_n = nn; }
    }
    sc[t] = 0;
    __syncthreads();
    int n = s_n;
    int gseg = b * CAP;
    int beg = seg ? gseg : s_beg;
    for (int e = t; e < n; e += 1024)
        atomicAdd(&sc[epart[gseg + e] >> 19], 1);
    __syncthreads();
    int v = sc[t];
    for (int off = 1; off < 1024; off <<= 1) {
        int add = (t >= off) ? sc[t - off] : 0;
        __syncthreads(); sc[t] += add; __syncthreads();
    }
    int start = sc[t] - v;             // exclusive, bucket-local slot
    rowp[b * 1025 + t] = beg + start;
    if (t == 1023) rowp[b * 1025 + 1024] = beg + n;
    cu[t] = start;
    __syncthreads();
    if (n <= BUF2) {
        for (int e = t; e < n; e += 1024) {
            unsigned p = epart[gseg + e];
            int slot = atomicAdd(&cu[p >> 19], 1);
            buf[slot] = p & 0x7FFFFu;   // just src (19 bits)
        }
        __syncthreads();
        // dense coalesced write-out
        for (int k = t; k < n; k += 1024)
            epart2[beg + k] = buf[k];
    } else if (!seg) {
        // overflow fallback (statistically unreachable): global scatter
        for (int e = t; e < n; e += 1024) {
            unsigned p = epart[gseg + e];
            int slot = atomicAdd(&cu[p >> 19], 1);
            epart2[beg + slot] = p & 0x7FFFFu;
        }
    }
    // seg && n>BUF2: unreachable (P ~ 1e-40); would leave segment unsorted.
}

// node init; in-degree free from rowp. Last block computes coeffs.
__global__ void init_nodes(const int* __restrict__ rl, const int* __restrict__ rowp,
                           float* __restrict__ dinv, float2* __restrict__ v0,
                           const int* __restrict__ flag, int N,
                           const float* __restrict__ W1, const float* __restrict__ b1,
                           const float* __restrict__ W2, const float* __restrict__ b2,
                           const float* __restrict__ W3, const float* __restrict__ b3,
                           const float* __restrict__ W4, const float* __restrict__ b4,
                           float* __restrict__ c) {
    __shared__ float p3[16], q3[16], r3[16];
    int t = threadIdx.x;
    if (blockIdx.x == gridDim.x - 1) {
        if (t == 0) {
            float p2[8], q2[8];
            for (int j = 0; j < 8; ++j) {
                float s1 = 0.f, s2 = 0.f;
                for (int k = 0; k < 4; ++k) {
                    float w = W2[k * 8 + j];
                    s1 += W1[k] * w;
                    s2 += b1[k] * w;
                }
                p2[j] = s1; q2[j] = s2;
            }
            for (int m = 0; m < 16; ++m) {
                float s1 = 0.f, s2 = 0.f, s3 = 0.f;
                for (int j = 0; j < 8; ++j) {
                    float w = W3[j * 16 + m];
                    s1 += p2[j] * w; s2 += q2[j] * w;
                    s3 += b2[j] * w;
                }
                p3[m] = s1; q3[m] = s2; r3[m] = s3;
            }
        }
        __syncthreads();
        if (t < 32) {
            float c4 = 0.f, c3 = 0.f, c2 = 0.f, c1 = 0.f;
            for (int k = 0; k < 16; ++k) {
                float w = W4[k * 32 + t];
                c4 += p3[k] * w; c3 += q3[k] * w; c2 += r3[k] * w;
                c1 += b3[k] * w;
            }
            c[t] = c4; c[32 + t] = c3; c[64 + t] = c2; c[96 + t] = c1;
        }
        return;
    }
    int i = blockIdx.x * blockDim.x + t;
    if (i < N) {
        int v = (*flag) ? rl[i] : rl[2 * i];
        int rb = (i >> 10) * 1025 + (i & 1023);
        float d = (float)(rowp[rb + 1] - rowp[rb]) + 1.0f;   // + self-loop
        dinv[i] = 1.0f / d;
        float rs = rsqrtf(d);
        float2 u; u.x = rs * ((float)v * (1.0f / 20000.0f)); u.y = rs;
        v0[i] = u;
    }
}

// one sweep: 8 lanes/node, register accumulate, x2 paired loads in flight.
__global__ void gather_csr(const unsigned* __restrict__ epart2, const int* __restrict__ rowp,
                           const float2* __restrict__ vin, float2* __restrict__ vout,
                           const float* __restrict__ dinv, float* __restrict__ zsave, int N) {
    int t = blockIdx.x * blockDim.x + threadIdx.x;
    int i = t >> 3, l = t & 7;
    if (i >= N) return;
    int rb = (i >> 10) * 1025 + (i & 1023);
    int beg = rowp[rb], end = rowp[rb + 1];
    float a = 0.f, b = 0.f;
    int j = beg + l;
    for (; j + 8 < end; j += 16) {         // two independent loads in flight
        int s0 = epart2[j];
        int s1 = epart2[j + 8];
        float2 u0 = vin[s0];
        float2 u1 = vin[s1];
        a += u0.x + u1.x; b += u0.y + u1.y;
    }
    if (j < end) {
        float2 u = vin[epart2[j]];
        a += u.x; b += u.y;
    }
    a += __shfl_xor(a, 1); b += __shfl_xor(b, 1);
    a += __shfl_xor(a, 2); b += __shfl_xor(b, 2);
    a += __shfl_xor(a, 4); b += __shfl_xor(b, 4);
    if (l == 0) {
        float2 self = vin[i];
        float di = dinv[i];
        float2 o; o.x = (a + self.x) * di; o.y = (b + self.y) * di;
        vout[i] = o;
        if (zsave) zsave[i] = o.y;
    }
}

// fused final sweep + epilogue (x-channel only; y of sweep 4 unused). All 8
// lanes hold the sum after the butterfly; each writes a float4 (128B/node
// contiguous). Valid only when epart2 is in workspace (out aliases d_out).
__global__ void gather_out(const unsigned* __restrict__ epart2, const int* __restrict__ rowp,
                           const float2* __restrict__ vin, const float* __restrict__ dinv,
                           const float* __restrict__ z1, const float* __restrict__ z2,
                           const float* __restrict__ z3, const float* __restrict__ c,
                           const float* __restrict__ b4, float* __restrict__ out, int N) {
    int t = blockIdx.x * blockDim.x + threadIdx.x;
    int i = t >> 3, l = t & 7;
    if (i >= N) return;
    int rb = (i >> 10) * 1025 + (i & 1023);
    int beg = rowp[rb], end = rowp[rb + 1];
    float a = 0.f;
    int j = beg + l;
    for (; j + 8 < end; j += 16) {
        int s0 = epart2[j];
        int s1 = epart2[j + 8];
        a += vin[s0].x + vin[s1].x;
    }
    if (j < end) a += vin[epart2[j]].x;
    a += __shfl_xor(a, 1);
    a += __shfl_xor(a, 2);
    a += __shfl_xor(a, 4);
    float di = dinv[i];
    float ox = (a + vin[i].x) * di;      // final A^4 x (scaled space)
    float sq = rsqrtf(di);               // = sqrt(deg)
    float zz1 = z1[i], zz2 = z2[i], zz3 = z3[i];
    float4 cc4 = *(const float4*)&c[l * 4];
    float4 cc3 = *(const float4*)&c[32 + l * 4];
    float4 cc2 = *(const float4*)&c[64 + l * 4];
    float4 cc1 = *(const float4*)&c[96 + l * 4];
    float4 bb  = *(const float4*)&b4[l * 4];
    float4 o4;
    o4.x = sq * (ox * cc4.x + zz3 * cc3.x + zz2 * cc2.x + zz1 * cc1.x) + bb.x;
    o4.y = sq * (ox * cc4.y + zz3 * cc3.y + zz2 * cc2.y + zz1 * cc1.y) + bb.y;
    o4.z = sq * (ox * cc4.z + zz3 * cc3.z + zz2 * cc2.z + zz1 * cc1.z) + bb.z;
    o4.w = sq * (ox * cc4.w + zz3 * cc3.w + zz2 * cc2.w + zz1 * cc1.w) + bb.w;
    *(float4*)&out[(size_t)i * 32 + l * 4] = o4;
}

// fallback epilogue (split path)
__global__ void write_out(const float2* __restrict__ v0, const float* __restrict__ z1,
                          const float* __restrict__ z2, const float* __restrict__ z3,
                          const float* __restrict__ dinv, const float* __restrict__ c,
                          const float* __restrict__ b4,
                          float* __restrict__ out, int N) {
    int t = blockIdx.x * blockDim.x + threadIdx.x;
    int i = t >> 5, f = t & 31;
    if (i < N) {
        float sq = rsqrtf(dinv[i]);  // = sqrt(deg)
        float v = sq * (v0[i].x * c[f] + z3[i] * c[32 + f] + z2[i] * c[64 + f]
                        + z1[i] * c[96 + f])
                  + b4[f];
        out[(size_t)i * 32 + f] = v;
    }
}

extern "C" void kernel_launch(void* const* d_in, const int* in_sizes, int n_in,
                              void* d_out, int out_size, void* d_ws, size_t ws_size,
                              hipStream_t stream) {
    const int N = in_sizes[0];
    const int E = in_sizes[1] / 2;
    const int* rl  = (const int*)d_in[0];
    const int* src = (const int*)d_in[1];
    const int* dst = src + E;
    const float* W1 = (const float*)d_in[2];
    const float* b1 = (const float*)d_in[3];
    const float* W2 = (const float*)d_in[4];
    const float* b2 = (const float*)d_in[5];
    const float* W3 = (const float*)d_in[6];
    const float* b3 = (const float*)d_in[7];
    const float* W4 = (const float*)d_in[8];
    const float* b4 = (const float*)d_in[9];

    const int gbNode = (N + 1023) / 1024;     // buckets containing nodes (489)

    // workspace layout
    char* w = (char*)d_ws;
    float2* v0   = (float2*)w;                w += (size_t)N * 8;
    float2* v1   = (float2*)w;                w += (size_t)N * 8;
    float*  dinv = (float*)w;                 w += (size_t)N * 4;
    float*  z1   = (float*)w;                 w += (size_t)N * 4;
    float*  z2   = (float*)w;                 w += (size_t)N * 4;
    float*  z3   = (float*)w;                 w += (size_t)N * 4;
    int*    rowp = (int*)w;                   w += (size_t)(gbNode * 1025 + 1) * 4;
    int*    cur  = (int*)w;                   w += NB * 4;
    float*  c    = (float*)w;                 w += 128 * 4;
    int*    flag = (int*)w;                   w += 16;
    // epart2 (compact) in workspace if it fits (enables fused gather_out)
    size_t used = (size_t)(w - (char*)d_ws);
    used = (used + 255) & ~(size_t)255;
    bool fits = (used + (size_t)E * 4) <= ws_size;
    // segmented epart always lives in d_out (NB*CAP*4 = 37.75 MB <= 64 MB)
    unsigned* epart  = (unsigned*)d_out;
    unsigned* epart2 = fits ? (unsigned*)((char*)d_ws + used) : epart;  // seg in-place if !fits

    probe_i64<<<2, BLK, 0, stream>>>(rl, flag, cur);

    // single-pass radix partition by dst bucket (atomic segment reservation)
    scatter<<<PB, SBLK, 0, stream>>>(src, dst, cur, epart, E);

    // within-bucket CSR (compact if fits, in-place segmented otherwise)
    csr_build<<<gbNode, 1024, 0, stream>>>(epart, cur, epart2, rowp, fits ? 0 : 1);

    const int nInit = (N + BLK - 1) / BLK;
    init_nodes<<<nInit + 1, BLK, 0, stream>>>(rl, rowp, dinv, v0, flag, N,
                                              W1, b1, W2, b2, W3, b3, W4, b4, c);

    // 4 propagation sweeps, ping-pong v0<->v1 (8 lanes/node)
    const int gbG = (8 * N + BLK - 1) / BLK;
    gather_csr<<<gbG, BLK, 0, stream>>>(epart2, rowp, v0, v1, dinv, z1, N);
    gather_csr<<<gbG, BLK, 0, stream>>>(epart2, rowp, v1, v0, dinv, z2, N);
    gather_csr<<<gbG, BLK, 0, stream>>>(epart2, rowp, v0, v1, dinv, z3, N);
    if (fits) {
        gather_out<<<gbG, BLK, 0, stream>>>(epart2, rowp, v1, dinv, z1, z2, z3,
                                            c, b4, (float*)d_out, N);
    } else {
        gather_csr<<<gbG, BLK, 0, stream>>>(epart2, rowp, v1, v0, dinv, (float*)nullptr, N);
        write_out<<<(N * 32 + BLK - 1) / BLK, BLK, 0, stream>>>(
            v0, z1, z2, z3, dinv, c, b4, (float*)d_out, N);
    }
}

// Round 8
// 385.362 us; speedup vs baseline: 1.3533x; 1.0463x over previous
//
#include <hip/hip_runtime.h>
#include <hip/hip_bf16.h>

// GCN 4-layer, linear network => collapse to:
// out = A^4 x0 * c4 + A^3 1 * c3 + A^2 1 * c2 + A 1 * c1 + b4,
// A = D^-1/2 (Adj+I) D^-1/2. Propagate in scaled space u' = D^-1 (Adj+I) u,
// epilogue multiplies sqrt(deg). Channels (x-path, ones-path) packed float2.
// Dtypes (R1-R4 verified): read_length int32, edge_index int32, W/b fp32, out fp32.
//
// R15: wave-segmented-scan gather. R14 counters: gather_csr 52us but FETCH
// (82MB) = 13us at BW and 8M random reqs = 13us at 1req/cy/CU -> bound is
// the rowp->epart2->vin dependent chain at MLP=2/lane. R13 lesson: LDS float
// atomics ~1 lane-op/cy -> per-edge atomics lose (4 ops/edge); but its
// block-per-bucket coalesced-sweep structure was right. New gather: edges
// (dst-sorted in bucket, full (d<<19|src) pack) swept 64/wave-window:
// 1 coalesced edge load + 1 wave-gather of vin (64 indep addrs in flight,
// no pointer chain) + 6-level shfl segmented scan by dst + LDS atomicAdd at
// segment TAILS only (~5/window, 12x fewer than R13). rowp DELETED: degree
// consumed inside csr_init (absorbs init_nodes), saving a kernel + 2MB.

#define BLK  256
#define SBLK 1024         // scatter block
#define NB   512          // buckets
#define BSH  10           // bucket = dst >> 10  (1024 nodes / bucket)
#define PB   512          // partition blocks
#define BUFCAP 15872      // scatter LDS sort buffer (chunk = ceil(8M/512) = 15625)
#define BUF2 18176        // csr LDS buffer (bucket mean 16384, sd ~128)
#define CAP  18432        // epart segment capacity per bucket (mean + 16 sigma)

// block 0: int64-layout probe (if rl were int64, every odd word is 0).
// block 1: zero the global bucket cursors.
__global__ void probe_i64(const int* __restrict__ rl32, int* __restrict__ flag,
                          int* __restrict__ cur) {
    __shared__ int sm[BLK];
    int t = threadIdx.x;
    if (blockIdx.x == 1) {
        for (int k = t; k < NB; k += BLK) cur[k] = 0;
        return;
    }
    int acc = 0;
    for (int k = t; k < 1024; k += blockDim.x)
        acc |= rl32[2 * k + 1];
    sm[t] = acc; __syncthreads();
    for (int off = BLK / 2; off > 0; off >>= 1) {
        if (t < off) sm[t] |= sm[t + off];
        __syncthreads();
    }
    if (t == 0) *flag = (sm[0] != 0) ? 1 : 0;   // 1 => int32 layout
}

// single-pass scatter: block-local LDS counting sort by bucket, one global
// atomicAdd per bucket run reserves space in the bucket's CAP segment; runs
// copied out dense+coalesced (lines written once, full).
__global__ __launch_bounds__(SBLK)
void scatter(const int* __restrict__ src, const int* __restrict__ dst,
             int* __restrict__ cur, unsigned* __restrict__ epart, int E) {
    __shared__ unsigned buf[BUFCAP];     // 62 KB
    __shared__ int h[NB];                // per-chunk counts
    __shared__ int c0[NB];               // scan / fill cursor
    __shared__ int gpos[NB];             // reserved global position
    int j = blockIdx.x, t = threadIdx.x;
    int chunk = (E + PB - 1) / PB;
    int beg = j * chunk, end = min(beg + chunk, E);
    for (int s = beg; s < end; s += BUFCAP) {
        int se = min(s + BUFCAP, end);
        for (int b = t; b < NB; b += SBLK) h[b] = 0;
        __syncthreads();
        for (int e = s + t; e < se; e += SBLK)
            atomicAdd(&h[((unsigned)dst[e]) >> BSH], 1);
        __syncthreads();
        // exclusive scan of h into c0 (NB entries, Hillis-Steele)
        if (t < NB) c0[t] = h[t];
        __syncthreads();
        for (int off = 1; off < NB; off <<= 1) {
            int add = 0;
            if (t < NB && t >= off) add = c0[t - off];
            __syncthreads();
            if (t < NB) c0[t] += add;
            __syncthreads();
        }
        if (t < NB) c0[t] -= h[t];
        __syncthreads();
        // fill LDS buffer sorted by bucket
        for (int e = s + t; e < se; e += SBLK) {
            unsigned d = (unsigned)dst[e];
            int b = d >> BSH;
            int slot = atomicAdd(&c0[b], 1);
            buf[slot] = ((d & 1023u) << 19) | (unsigned)src[e];
        }
        __syncthreads();
        // reserve global space: one thread per bucket
        if (t < NB) {
            int n = h[t];
            gpos[t] = (n > 0) ? atomicAdd(&cur[t], n) : 0;
        }
        __syncthreads();
        // copy out: wave w handles buckets w, w+16, ...
        int w = t >> 6, lane = t & 63;
        for (int b = w; b < NB; b += (SBLK >> 6)) {
            int n = h[b];
            int lo = c0[b] - n;          // c0 back to inclusive after fill
            int gp = gpos[b];
            int left = CAP - gp;         // overflow guard (unreachable)
            if (left < 0) left = 0;
            if (n > left) n = left;
            unsigned gb = (unsigned)b * CAP + (unsigned)gp;
            for (int k = lane; k < n; k += 64)
                epart[gb + k] = buf[lo + k];
        }
        __syncthreads();
    }
}

// R15: per-bucket dst-sort (keeps full pack) + compact write + bstart; node
// init fused (degree = pre-scan count); coeffs in the last block.
// seg=0: compact epart2 (disjoint). seg=1: sorted in place in the segment.
__global__ __launch_bounds__(1024)
void csr_init(const unsigned* __restrict__ epart, const int* __restrict__ cur,
              const int* __restrict__ rl, const int* __restrict__ flag,
              unsigned* __restrict__ epart2, int* __restrict__ bstart,
              float* __restrict__ dinv, float2* __restrict__ v0, int N,
              const float* __restrict__ W1, const float* __restrict__ b1,
              const float* __restrict__ W2, const float* __restrict__ b2,
              const float* __restrict__ W3, const float* __restrict__ b3,
              const float* __restrict__ W4, const float* __restrict__ b4,
              float* __restrict__ c, int seg) {
    __shared__ unsigned buf[BUF2];     // 71 KB
    __shared__ int sc[1024];
    __shared__ int cu[1024];
    __shared__ int s_beg, s_n;
    int b = blockIdx.x, t = threadIdx.x;
    if (b == gridDim.x - 1) {
        // coeffs block
        __shared__ float p3[16], q3[16], r3[16];
        if (t == 0) {
            float p2[8], q2[8];
            for (int j = 0; j < 8; ++j) {
                float s1 = 0.f, s2 = 0.f;
                for (int k = 0; k < 4; ++k) {
                    float w = W2[k * 8 + j];
                    s1 += W1[k] * w;
                    s2 += b1[k] * w;
                }
                p2[j] = s1; q2[j] = s2;
            }
            for (int m = 0; m < 16; ++m) {
                float s1 = 0.f, s2 = 0.f, s3 = 0.f;
                for (int j = 0; j < 8; ++j) {
                    float w = W3[j * 16 + m];
                    s1 += p2[j] * w; s2 += q2[j] * w;
                    s3 += b2[j] * w;
                }
                p3[m] = s1; q3[m] = s2; r3[m] = s3;
            }
        }
        __syncthreads();
        if (t < 32) {
            float c4 = 0.f, c3 = 0.f, c2 = 0.f, c1 = 0.f;
            for (int k = 0; k < 16; ++k) {
                float w = W4[k * 32 + t];
                c4 += p3[k] * w; c3 += q3[k] * w; c2 += r3[k] * w;
                c1 += b3[k] * w;
            }
            c[t] = c4; c[32 + t] = c3; c[64 + t] = c2; c[96 + t] = c1;
        }
        return;
    }
    if (t < 64) {
        int pre = 0, nn = 0;
        for (int k = t; k < NB; k += 64) {
            int v = min(cur[k], CAP);
            if (k < b) pre += v;
            if (k == b) nn = v;
        }
        for (int off = 1; off < 64; off <<= 1) {
            pre += __shfl_xor(pre, off);
            nn  += __shfl_xor(nn, off);
        }
        if (t == 0) { s_beg = pre; s_n = nn; }
    }
    sc[t] = 0;
    __syncthreads();
    int n = s_n;
    int gseg = b * CAP;
    int beg = seg ? gseg : s_beg;
    if (t == 0) bstart[b] = beg;
    if (b == gridDim.x - 2 && t == 1) bstart[b + 1] = beg + n;
    for (int e = t; e < n; e += 1024)
        atomicAdd(&sc[epart[gseg + e] >> 19], 1);
    __syncthreads();
    int v = sc[t];
    for (int off = 1; off < 1024; off <<= 1) {
        int add = (t >= off) ? sc[t - off] : 0;
        __syncthreads(); sc[t] += add; __syncthreads();
    }
    cu[t] = sc[t] - v;                 // exclusive, bucket-local slot
    // fused node init: degree = v (pre-scan count)
    int gi = (b << 10) + t;
    if (gi < N) {
        int rv = (*flag) ? rl[gi] : rl[2 * gi];
        float d = (float)v + 1.0f;     // + self-loop
        dinv[gi] = 1.0f / d;
        float rs = rsqrtf(d);
        float2 u; u.x = rs * ((float)rv * (1.0f / 20000.0f)); u.y = rs;
        v0[gi] = u;
    }
    __syncthreads();
    if (n <= BUF2) {
        for (int e = t; e < n; e += 1024) {
            unsigned p = epart[gseg + e];
            int slot = atomicAdd(&cu[p >> 19], 1);
            buf[slot] = p;             // FULL pack (dst|src) kept
        }
        __syncthreads();
        for (int k = t; k < n; k += 1024)
            epart2[beg + k] = buf[k];  // dense coalesced write-out
    } else if (!seg) {
        for (int e = t; e < n; e += 1024) {
            unsigned p = epart[gseg + e];
            int slot = atomicAdd(&cu[p >> 19], 1);
            epart2[beg + slot] = p;
        }
    }
    // seg && n>BUF2: unreachable (P ~ 1e-40).
}

// R15 sweep: block per bucket; waves sweep 64-edge windows of the dst-sorted
// run. Coalesced edge load + 64-address wave-gather + segmented scan by dst
// + LDS atomicAdd at segment tails only.
__global__ __launch_bounds__(1024)
void gather_seg(const unsigned* __restrict__ ep, const int* __restrict__ bstart,
                const int* __restrict__ cur, int seg,
                const float2* __restrict__ vin, float2* __restrict__ vout,
                const float* __restrict__ dinv, float* __restrict__ zsave, int N) {
    __shared__ float ax[1024];
    __shared__ float ay[1024];
    int b = blockIdx.x, t = threadIdx.x;
    ax[t] = 0.f; ay[t] = 0.f;
    __syncthreads();
    int beg = bstart[b];
    int n = seg ? min(cur[b], CAP) : (bstart[b + 1] - beg);
    int end = beg + n;
    int lane = t & 63;
    for (int base = beg + (t - lane); base < end; base += 1024) {
        int e = base + lane;
        unsigned p = (e < end) ? ep[e] : 0xFFFFFFFFu;  // sentinel key 8191
        int key = (int)(p >> 19);
        float vx = 0.f, vy = 0.f;
        if (e < end) {
            float2 u = vin[p & 0x7FFFFu];
            vx = u.x; vy = u.y;
        }
#pragma unroll
        for (int off = 1; off < 64; off <<= 1) {
            float ox = __shfl_up(vx, off);
            float oy = __shfl_up(vy, off);
            int ok = __shfl_up(key, off);
            bool act = (lane >= off) && (ok == key);
            vx += act ? ox : 0.f;
            vy += act ? oy : 0.f;
        }
        int nk = __shfl_down(key, 1);
        bool tail = (lane == 63) || (nk != key);
        if (tail && key < 1024) {
            atomicAdd(&ax[key], vx);
            atomicAdd(&ay[key], vy);
        }
    }
    __syncthreads();
    int gi = (b << 10) + t;
    if (gi < N) {
        float2 self = vin[gi];
        float di = dinv[gi];
        float2 o; o.x = (ax[t] + self.x) * di; o.y = (ay[t] + self.y) * di;
        vout[gi] = o;
        if (zsave) zsave[gi] = o.y;
    }
}

// R15 fused final sweep + epilogue (x-channel only). After accumulation,
// finalized ox and sqrt(deg) are republished in LDS; epilogue goes
// channel-parallel (32 threads/node) for coalesced 128B stores. Valid only
// when epart2 is in workspace (out aliases d_out).
__global__ __launch_bounds__(1024)
void gather_out_seg(const unsigned* __restrict__ ep, const int* __restrict__ bstart,
                    const float2* __restrict__ vin, const float* __restrict__ dinv,
                    const float* __restrict__ z1, const float* __restrict__ z2,
                    const float* __restrict__ z3, const float* __restrict__ c,
                    const float* __restrict__ b4, float* __restrict__ out, int N) {
    __shared__ float ax[1024];
    __shared__ float sqs[1024];
    int b = blockIdx.x, t = threadIdx.x;
    ax[t] = 0.f;
    __syncthreads();
    int beg = bstart[b], end = bstart[b + 1];
    int lane = t & 63;
    for (int base = beg + (t - lane); base < end; base += 1024) {
        int e = base + lane;
        unsigned p = (e < end) ? ep[e] : 0xFFFFFFFFu;
        int key = (int)(p >> 19);
        float vx = 0.f;
        if (e < end) vx = vin[p & 0x7FFFFu].x;
#pragma unroll
        for (int off = 1; off < 64; off <<= 1) {
            float ox = __shfl_up(vx, off);
            int ok = __shfl_up(key, off);
            bool act = (lane >= off) && (ok == key);
            vx += act ? ox : 0.f;
        }
        int nk = __shfl_down(key, 1);
        bool tail = (lane == 63) || (nk != key);
        if (tail && key < 1024) atomicAdd(&ax[key], vx);
    }
    __syncthreads();
    int gi = (b << 10) + t;
    float ox = 0.f, sq = 0.f;
    if (gi < N) {
        float di = dinv[gi];
        ox = (ax[t] + vin[gi].x) * di;   // final A^4 x (scaled space)
        sq = rsqrtf(di);                 // = sqrt(deg)
    }
    __syncthreads();
    ax[t] = ox; sqs[t] = sq;             // own slot only
    __syncthreads();
    // channel-parallel epilogue
    int f = t & 31, half = t >> 5;       // half in [0,32)
    float c4 = c[f], c3 = c[32 + f], c2 = c[64 + f], c1 = c[96 + f], bb = b4[f];
    int base_node = b << 10;
    for (int p = 0; p < 32; ++p) {
        int ln = p * 32 + half;
        int g = base_node + ln;
        if (g < N) {
            float zz1 = z1[g], zz2 = z2[g], zz3 = z3[g];
            float val = sqs[ln] * (ax[ln] * c4 + zz3 * c3 + zz2 * c2 + zz1 * c1) + bb;
            out[(size_t)g * 32 + f] = val;
        }
    }
}

// fallback epilogue (split path)
__global__ void write_out(const float2* __restrict__ v0, const float* __restrict__ z1,
                          const float* __restrict__ z2, const float* __restrict__ z3,
                          const float* __restrict__ dinv, const float* __restrict__ c,
                          const float* __restrict__ b4,
                          float* __restrict__ out, int N) {
    int t = blockIdx.x * blockDim.x + threadIdx.x;
    int i = t >> 5, f = t & 31;
    if (i < N) {
        float sq = rsqrtf(dinv[i]);  // = sqrt(deg)
        float v = sq * (v0[i].x * c[f] + z3[i] * c[32 + f] + z2[i] * c[64 + f]
                        + z1[i] * c[96 + f])
                  + b4[f];
        out[(size_t)i * 32 + f] = v;
    }
}

extern "C" void kernel_launch(void* const* d_in, const int* in_sizes, int n_in,
                              void* d_out, int out_size, void* d_ws, size_t ws_size,
                              hipStream_t stream) {
    const int N = in_sizes[0];
    const int E = in_sizes[1] / 2;
    const int* rl  = (const int*)d_in[0];
    const int* src = (const int*)d_in[1];
    const int* dst = src + E;
    const float* W1 = (const float*)d_in[2];
    const float* b1 = (const float*)d_in[3];
    const float* W2 = (const float*)d_in[4];
    const float* b2 = (const float*)d_in[5];
    const float* W3 = (const float*)d_in[6];
    const float* b3 = (const float*)d_in[7];
    const float* W4 = (const float*)d_in[8];
    const float* b4 = (const float*)d_in[9];

    const int gbNode = (N + 1023) / 1024;     // buckets containing nodes (489)

    // workspace layout
    char* w = (char*)d_ws;
    float2* v0   = (float2*)w;                w += (size_t)N * 8;
    float2* v1   = (float2*)w;                w += (size_t)N * 8;
    float*  dinv = (float*)w;                 w += (size_t)N * 4;
    float*  z1   = (float*)w;                 w += (size_t)N * 4;
    float*  z2   = (float*)w;                 w += (size_t)N * 4;
    float*  z3   = (float*)w;                 w += (size_t)N * 4;
    int*    bstart = (int*)w;                 w += (NB + 1) * 4;
    int*    cur  = (int*)w;                   w += NB * 4;
    float*  c    = (float*)w;                 w += 128 * 4;
    int*    flag = (int*)w;                   w += 16;
    // epart2 (compact, dst-sorted) in workspace if it fits
    size_t used = (size_t)(w - (char*)d_ws);
    used = (used + 255) & ~(size_t)255;
    bool fits = (used + (size_t)E * 4) <= ws_size;
    // segmented epart always lives in d_out (NB*CAP*4 = 37.75 MB <= 64 MB)
    unsigned* epart  = (unsigned*)d_out;
    unsigned* epart2 = fits ? (unsigned*)((char*)d_ws + used) : epart;  // in-place if !fits
    const int seg = fits ? 0 : 1;

    probe_i64<<<2, BLK, 0, stream>>>(rl, flag, cur);

    // single-pass radix partition by dst bucket (atomic segment reservation)
    scatter<<<PB, SBLK, 0, stream>>>(src, dst, cur, epart, E);

    // within-bucket dst-sort + bstart + fused node init + coeffs
    csr_init<<<gbNode + 1, 1024, 0, stream>>>(epart, cur, rl, flag, epart2, bstart,
                                              dinv, v0, N,
                                              W1, b1, W2, b2, W3, b3, W4, b4, c, seg);

    // 4 propagation sweeps, ping-pong v0<->v1 (wave-segmented scan)
    gather_seg<<<gbNode, 1024, 0, stream>>>(epart2, bstart, cur, seg, v0, v1, dinv, z1, N);
    gather_seg<<<gbNode, 1024, 0, stream>>>(epart2, bstart, cur, seg, v1, v0, dinv, z2, N);
    gather_seg<<<gbNode, 1024, 0, stream>>>(epart2, bstart, cur, seg, v0, v1, dinv, z3, N);
    if (fits) {
        gather_out_seg<<<gbNode, 1024, 0, stream>>>(epart2, bstart, v1, dinv,
                                                    z1, z2, z3, c, b4,
                                                    (float*)d_out, N);
    } else {
        gather_seg<<<gbNode, 1024, 0, stream>>>(epart2, bstart, cur, seg, v1, v0, dinv,
                                                (float*)nullptr, N);
        write_out<<<(N * 32 + BLK - 1) / BLK, BLK, 0, stream>>>(
            v0, z1, z2, z3, dinv, c, b4, (float*)d_out, N);
    }
}